// Round 1
// baseline (845.588 us; speedup 1.0000x reference)
//
#include <hip/hip_runtime.h>
#include <hip/hip_bf16.h>
#include <cstdint>

// ---------- types ----------
typedef __attribute__((ext_vector_type(4))) float f32x4;
typedef __attribute__((ext_vector_type(8))) short bf16x8;   // 8 bf16 = 4 VGPRs
typedef __attribute__((ext_vector_type(4))) short s16x4;

// fp32 -> bf16 round-to-nearest-even (inputs are finite; no NaN path needed)
__device__ __forceinline__ short f2bf(float f) {
    union { float f; unsigned u; } v; v.f = f;
    unsigned r = v.u + 0x7FFFu + ((v.u >> 16) & 1u);
    return (short)(r >> 16);
}

// ---------- elementwise cast x: fp32 -> bf16 ----------
__global__ __launch_bounds__(256) void cast_bf16(const float* __restrict__ in,
                                                 short* __restrict__ out, long n) {
    long i = ((long)blockIdx.x * 256 + threadIdx.x) * 4;
    if (i + 3 < n) {
        float4 v = *(const float4*)(in + i);
        s16x4 o;
        o[0] = f2bf(v.x); o[1] = f2bf(v.y); o[2] = f2bf(v.z); o[3] = f2bf(v.w);
        *(s16x4*)(out + i) = o;
    }
}

// ---------- transpose + cast: in fp32 [E][R][Cc] -> out bf16 [E][Cc][R] ----------
__global__ __launch_bounds__(256) void transpose_cast(const float* __restrict__ in,
                                                      short* __restrict__ out,
                                                      int R, int Cc) {
    __shared__ float t[32][33];                 // +1 pad: no bank conflicts
    const size_t eoff = (size_t)blockIdx.z * R * Cc;
    in  += eoff;
    out += eoff;
    const int c0 = blockIdx.x * 32, r0 = blockIdx.y * 32;
    const int tx = threadIdx.x, ty = threadIdx.y;
    #pragma unroll
    for (int i = ty; i < 32; i += 8)
        t[i][tx] = in[(size_t)(r0 + i) * Cc + c0 + tx];
    __syncthreads();
    #pragma unroll
    for (int i = ty; i < 32; i += 8)
        out[(size_t)(c0 + i) * R + r0 + tx] = f2bf(t[tx][i]);
}

// ---------- async global -> LDS staging of a 128x32 bf16 tile ----------
// src is row-major with leading dimension ld (elements); tile rows are the
// 128 "non-K" rows, 32 K elements each. LDS layout is flat [row][k], no pad
// (global_load_lds requires LDS dest = wave-uniform base + lane*16).
__device__ __forceinline__ void stage_tile(const short* __restrict__ g,
                                           short* lds, int ld,
                                           int wave, int lane) {
    #pragma unroll
    for (int i = 0; i < 2; ++i) {
        const int c   = i * 256 + wave * 64 + lane;   // chunk id, 16B chunks
        const int row = c >> 2;
        const int kc  = (c & 3) << 3;
        const short* gp = g + (size_t)row * ld + kc;
        short* lp = lds + (size_t)(i * 256 + wave * 64) * 8;  // wave-uniform base
        __builtin_amdgcn_global_load_lds(
            (const __attribute__((address_space(1))) void*)gp,
            (__attribute__((address_space(3))) void*)lp, 16, 0, 0);
    }
}

// ---------- GEMM: C[e] = A[e] (MxK, row-major) * Bt[e]^T (Bt is NxK row-major)
// FUSE=1: C is bf16, gelu(exact) applied.  FUSE=0: C is fp32.
template <int FUSE>
__global__ __launch_bounds__(256) void gemm_bt(const short* __restrict__ A,
                                               const short* __restrict__ Bt,
                                               void* __restrict__ Cout,
                                               int M, int N, int K) {
    __shared__ short As[128 * 32];
    __shared__ short Bs[128 * 32];
    const int tid  = threadIdx.x;
    const int lane = tid & 63;
    const int wave = tid >> 6;
    const int e    = blockIdx.z;
    A  += (size_t)e * M * K;
    Bt += (size_t)e * N * K;
    const int m0 = blockIdx.y * 128;
    const int n0 = blockIdx.x * 128;
    const int wm = (wave >> 1) * 64;   // wave sub-tile origin within 128x128
    const int wn = (wave & 1) * 64;

    f32x4 acc[4][4] = {};

    const short* Ab = A  + (size_t)m0 * K;
    const short* Bb = Bt + (size_t)n0 * K;

    const int rA = wm + (lane & 15);
    const int rB = wn + (lane & 15);
    const int kc = (lane >> 4) << 3;

    for (int k0 = 0; k0 < K; k0 += 32) {
        stage_tile(Ab + k0, As, K, wave, lane);
        stage_tile(Bb + k0, Bs, K, wave, lane);
        __syncthreads();                       // compiler drains vmcnt before barrier

        bf16x8 af[4], bf[4];
        #pragma unroll
        for (int t = 0; t < 4; ++t)
            af[t] = *(const bf16x8*)&As[(rA + t * 16) * 32 + kc];
        #pragma unroll
        for (int t = 0; t < 4; ++t)
            bf[t] = *(const bf16x8*)&Bs[(rB + t * 16) * 32 + kc];

        #pragma unroll
        for (int i = 0; i < 4; ++i)
            #pragma unroll
            for (int j = 0; j < 4; ++j)
                acc[i][j] = __builtin_amdgcn_mfma_f32_16x16x32_bf16(
                    af[i], bf[j], acc[i][j], 0, 0, 0);
        __syncthreads();
    }

    // epilogue — C/D layout (verified m89/m91): col = lane&15, row = (lane>>4)*4 + reg
    const int r0 = (lane >> 4) << 2;
    const int cL = lane & 15;
    if (FUSE) {
        short* C = (short*)Cout + (size_t)e * M * N;
        #pragma unroll
        for (int i = 0; i < 4; ++i)
            #pragma unroll
            for (int j = 0; j < 4; ++j)
                #pragma unroll
                for (int r = 0; r < 4; ++r) {
                    const int row = m0 + wm + i * 16 + r0 + r;
                    const int col = n0 + wn + j * 16 + cL;
                    float v = acc[i][j][r];
                    v = 0.5f * v * (1.0f + erff(v * 0.70710678118654752f));
                    C[(size_t)row * N + col] = f2bf(v);
                }
    } else {
        float* C = (float*)Cout + (size_t)e * M * N;
        #pragma unroll
        for (int i = 0; i < 4; ++i)
            #pragma unroll
            for (int j = 0; j < 4; ++j)
                #pragma unroll
                for (int r = 0; r < 4; ++r) {
                    const int row = m0 + wm + i * 16 + r0 + r;
                    const int col = n0 + wn + j * 16 + cL;
                    C[(size_t)row * N + col] = acc[i][j][r];
                }
    }
}

// ---------- launch ----------
extern "C" void kernel_launch(void* const* d_in, const int* in_sizes, int n_in,
                              void* d_out, int out_size, void* d_ws, size_t ws_size,
                              hipStream_t stream) {
    constexpr int E = 8, Ct = 2048, H = 1024, I = 4096;   // G = 1

    const float* x  = (const float*)d_in[0];   // [1,E,Ct,H]
    const float* wi = (const float*)d_in[1];   // [E,H,I]
    const float* wo = (const float*)d_in[2];   // [E,I,H]
    float* out = (float*)d_out;                // [1,E,Ct,H] fp32

    char* ws = (char*)d_ws;
    // ws layout (bytes): xb 32MiB | wiT 64MiB | woT 64MiB | h 128MiB = 288MiB
    short* xb  = (short*)(ws);
    short* wiT = (short*)(ws + (size_t)33554432);
    short* woT = (short*)(ws + (size_t)100663296);
    short* h   = (short*)(ws + (size_t)167772160);

    // 1) x fp32 -> bf16 (layout unchanged: [E][Ct][H] row-major)
    {
        long n = (long)E * Ct * H;             // 16,777,216
        cast_bf16<<<dim3((unsigned)(n / 1024)), dim3(256), 0, stream>>>(x, xb, n);
    }
    // 2) wi [E][H][I] -> wiT [E][I][H] bf16
    transpose_cast<<<dim3(I / 32, H / 32, E), dim3(32, 8), 0, stream>>>(wi, wiT, H, I);
    // 3) wo [E][I][H] -> woT [E][H][I] bf16
    transpose_cast<<<dim3(H / 32, I / 32, E), dim3(32, 8), 0, stream>>>(wo, woT, I, H);

    // 4) h = gelu(x @ wi):  M=Ct, N=I, K=H ; A=xb, Bt=wiT (NxK) ; bf16 out
    gemm_bt<1><<<dim3(I / 128, Ct / 128, E), dim3(256), 0, stream>>>(
        xb, wiT, (void*)h, Ct, I, H);

    // 5) out = h @ wo:      M=Ct, N=H, K=I ; A=h,  Bt=woT (NxK) ; fp32 out
    gemm_bt<0><<<dim3(H / 128, Ct / 128, E), dim3(256), 0, stream>>>(
        h, woT, (void*)out, Ct, H, I);
}

// Round 2
// 719.203 us; speedup vs baseline: 1.1757x; 1.1757x over previous
//
#include <hip/hip_runtime.h>
#include <hip/hip_bf16.h>
#include <cstdint>

// ---------- types ----------
typedef __attribute__((ext_vector_type(4))) float f32x4;
typedef __attribute__((ext_vector_type(8))) short bf16x8;   // 8 bf16 = 4 VGPRs
typedef __attribute__((ext_vector_type(4))) short s16x4;
typedef __attribute__((ext_vector_type(8))) short s16x8;

// fp32 -> bf16 round-to-nearest-even (inputs are finite; no NaN path needed)
__device__ __forceinline__ short f2bf(float f) {
    union { float f; unsigned u; } v; v.f = f;
    unsigned r = v.u + 0x7FFFu + ((v.u >> 16) & 1u);
    return (short)(r >> 16);
}

// ---------- elementwise cast x: fp32 -> bf16, 8 elem/thread ----------
__global__ __launch_bounds__(256) void cast_bf16(const float* __restrict__ in,
                                                 short* __restrict__ out, long n) {
    long i = ((long)blockIdx.x * 256 + threadIdx.x) * 8;
    if (i + 7 < n) {
        float4 a = *(const float4*)(in + i);
        float4 b = *(const float4*)(in + i + 4);
        s16x8 o;
        o[0] = f2bf(a.x); o[1] = f2bf(a.y); o[2] = f2bf(a.z); o[3] = f2bf(a.w);
        o[4] = f2bf(b.x); o[5] = f2bf(b.y); o[6] = f2bf(b.z); o[7] = f2bf(b.w);
        *(s16x8*)(out + i) = o;                     // 16B store
    }
}

// ---------- transpose + cast: in fp32 [E][R][C] -> out bf16 [E][C][R] ----------
// 64x64 tile, float4 loads, short4 stores (128B contiguous per out-row segment)
__global__ __launch_bounds__(256) void transpose_cast(const float* __restrict__ in,
                                                      short* __restrict__ out,
                                                      int R, int C) {
    __shared__ float t[64][65];                 // +1 pad
    const size_t eoff = (size_t)blockIdx.z * R * C;
    in  += eoff;
    out += eoff;
    const int c0 = blockIdx.x * 64, r0 = blockIdx.y * 64;
    const int tid = threadIdx.x;
    const int rr  = tid >> 4;                   // 0..15
    const int cc4 = (tid & 15) * 4;             // 0..60 step 4
    #pragma unroll
    for (int i = 0; i < 4; ++i) {
        const int row = i * 16 + rr;
        float4 v = *(const float4*)(in + (size_t)(r0 + row) * C + c0 + cc4);
        t[row][cc4 + 0] = v.x; t[row][cc4 + 1] = v.y;
        t[row][cc4 + 2] = v.z; t[row][cc4 + 3] = v.w;
    }
    __syncthreads();
    #pragma unroll
    for (int i = 0; i < 4; ++i) {
        const int oc = i * 16 + rr;             // C-index = output row
        s16x4 o;
        o[0] = f2bf(t[cc4 + 0][oc]);
        o[1] = f2bf(t[cc4 + 1][oc]);
        o[2] = f2bf(t[cc4 + 2][oc]);
        o[3] = f2bf(t[cc4 + 3][oc]);
        *(s16x4*)(out + (size_t)(c0 + oc) * R + r0 + cc4) = o;   // 8B store
    }
}

// ---------- async global -> LDS staging of a 128x64 bf16 tile ----------
// LDS layout: flat [row][8 chunks of 16B], with chunk slot XOR-swizzled by
// (row&7) to kill ds_read bank conflicts. global_load_lds dest must be
// wave-uniform base + lane*16, so the swizzle is applied on the GLOBAL side.
__device__ __forceinline__ void stage_tile64(const short* __restrict__ g,
                                             short* lds, int ld,
                                             int wave, int lane) {
    #pragma unroll
    for (int i = 0; i < 4; ++i) {
        const int c    = i * 256 + wave * 64 + lane;   // 16B chunk id, 0..1023
        const int row  = c >> 3;
        const int slot = c & 7;
        const int gkc  = (slot ^ (row & 7)) << 3;      // global k-offset (shorts)
        const short* gp = g + (size_t)row * ld + gkc;
        short* lp = lds + (size_t)(i * 256 + wave * 64) * 8;  // wave-uniform base
        __builtin_amdgcn_global_load_lds(
            (const __attribute__((address_space(1))) void*)gp,
            (__attribute__((address_space(3))) void*)lp, 16, 0, 0);
    }
}

// ---------- GEMM: C[e] = A[e] (MxK, row-major) * Bt[e]^T (Bt is NxK row-major)
// BK=64: 32 MFMA per barrier-pair. FUSE=1: bf16 out + exact gelu. FUSE=0: fp32.
template <int FUSE>
__global__ __launch_bounds__(256) void gemm_bt(const short* __restrict__ A,
                                               const short* __restrict__ Bt,
                                               void* __restrict__ Cout,
                                               int M, int N, int K) {
    __shared__ short As[128 * 64];
    __shared__ short Bs[128 * 64];
    const int tid  = threadIdx.x;
    const int lane = tid & 63;
    const int wave = tid >> 6;
    const int e    = blockIdx.z;
    A  += (size_t)e * M * K;
    Bt += (size_t)e * N * K;

    // band-of-4 swizzle: 4 M-tiles sweep all N together (L2 locality)
    const int gridN = gridDim.x;
    const int lin   = blockIdx.y * gridN + blockIdx.x;
    const int band  = lin / (4 * gridN);
    const int rem   = lin - band * 4 * gridN;
    const int m0 = (band * 4 + (rem & 3)) * 128;
    const int n0 = (rem >> 2) * 128;

    const int wm = (wave >> 1) * 64;   // wave sub-tile origin within 128x128
    const int wn = (wave & 1) * 64;

    f32x4 acc[4][4] = {};

    const short* Ab = A  + (size_t)m0 * K;
    const short* Bb = Bt + (size_t)n0 * K;

    const int rA   = wm + (lane & 15);
    const int rB   = wn + (lane & 15);
    const int quad = lane >> 4;                 // 0..3

    for (int k0 = 0; k0 < K; k0 += 64) {
        stage_tile64(Ab + k0, As, K, wave, lane);
        stage_tile64(Bb + k0, Bs, K, wave, lane);
        __syncthreads();                        // drains vmcnt before barrier

        #pragma unroll
        for (int s = 0; s < 2; ++s) {
            const int j = s * 4 + quad;         // logical 16B chunk within row
            bf16x8 af[4], bf[4];
            #pragma unroll
            for (int t = 0; t < 4; ++t) {
                const int ra = rA + t * 16;
                af[t] = *(const bf16x8*)&As[ra * 64 + ((j ^ (ra & 7)) << 3)];
            }
            #pragma unroll
            for (int t = 0; t < 4; ++t) {
                const int rb = rB + t * 16;
                bf[t] = *(const bf16x8*)&Bs[rb * 64 + ((j ^ (rb & 7)) << 3)];
            }
            #pragma unroll
            for (int i = 0; i < 4; ++i)
                #pragma unroll
                for (int jj = 0; jj < 4; ++jj)
                    acc[i][jj] = __builtin_amdgcn_mfma_f32_16x16x32_bf16(
                        af[i], bf[jj], acc[i][jj], 0, 0, 0);
        }
        __syncthreads();
    }

    // epilogue — C/D layout (m89/m91): col = lane&15, row = (lane>>4)*4 + reg
    const int r0 = quad << 2;
    const int cL = lane & 15;
    if (FUSE) {
        short* C = (short*)Cout + (size_t)e * M * N;
        #pragma unroll
        for (int i = 0; i < 4; ++i)
            #pragma unroll
            for (int j = 0; j < 4; ++j)
                #pragma unroll
                for (int r = 0; r < 4; ++r) {
                    const int row = m0 + wm + i * 16 + r0 + r;
                    const int col = n0 + wn + j * 16 + cL;
                    float v = acc[i][j][r];
                    v = 0.5f * v * (1.0f + erff(v * 0.70710678118654752f));
                    C[(size_t)row * N + col] = f2bf(v);
                }
    } else {
        float* C = (float*)Cout + (size_t)e * M * N;
        #pragma unroll
        for (int i = 0; i < 4; ++i)
            #pragma unroll
            for (int j = 0; j < 4; ++j)
                #pragma unroll
                for (int r = 0; r < 4; ++r) {
                    const int row = m0 + wm + i * 16 + r0 + r;
                    const int col = n0 + wn + j * 16 + cL;
                    C[(size_t)row * N + col] = acc[i][j][r];
                }
    }
}

// ---------- launch ----------
extern "C" void kernel_launch(void* const* d_in, const int* in_sizes, int n_in,
                              void* d_out, int out_size, void* d_ws, size_t ws_size,
                              hipStream_t stream) {
    constexpr int E = 8, Ct = 2048, H = 1024, I = 4096;   // G = 1

    const float* x  = (const float*)d_in[0];   // [1,E,Ct,H]
    const float* wi = (const float*)d_in[1];   // [E,H,I]
    const float* wo = (const float*)d_in[2];   // [E,I,H]
    float* out = (float*)d_out;                // [1,E,Ct,H] fp32

    char* ws = (char*)d_ws;
    // ws layout (bytes): xb 32MiB | wiT 64MiB | woT 64MiB | h 128MiB = 288MiB
    short* xb  = (short*)(ws);
    short* wiT = (short*)(ws + (size_t)33554432);
    short* woT = (short*)(ws + (size_t)100663296);
    short* h   = (short*)(ws + (size_t)167772160);

    // 1) x fp32 -> bf16 (layout unchanged: [E][Ct][H] row-major)
    {
        long n = (long)E * Ct * H;             // 16,777,216
        cast_bf16<<<dim3((unsigned)(n / 2048)), dim3(256), 0, stream>>>(x, xb, n);
    }
    // 2) wi [E][H][I] -> wiT [E][I][H] bf16
    transpose_cast<<<dim3(I / 64, H / 64, E), dim3(256), 0, stream>>>(wi, wiT, H, I);
    // 3) wo [E][I][H] -> woT [E][H][I] bf16
    transpose_cast<<<dim3(H / 64, I / 64, E), dim3(256), 0, stream>>>(wo, woT, I, H);

    // 4) h = gelu(x @ wi):  M=Ct, N=I, K=H ; A=xb, Bt=wiT (NxK) ; bf16 out
    gemm_bt<1><<<dim3(I / 128, Ct / 128, E), dim3(256), 0, stream>>>(
        xb, wiT, (void*)h, Ct, I, H);

    // 5) out = h @ wo:      M=Ct, N=H, K=I ; A=h,  Bt=woT (NxK) ; fp32 out
    gemm_bt<0><<<dim3(H / 128, Ct / 128, E), dim3(256), 0, stream>>>(
        h, woT, (void*)out, Ct, H, I);
}